// Round 5
// baseline (100.883 us; speedup 1.0000x reference)
//
#include <hip/hip_runtime.h>

// PositionalEncoding: out[b,s,d] = x[b,s,d] + (positions[b,s] >= 0 ? pe[positions[b,s], d] : 0)
// B=256, S=365, D=512, fp32. Memory-bound: read x (191 MB) + write out (191 MB);
// positions (373 KB) and pe (747 KB) are cache-resident.
//
// Round 4 -> 5: keep the flat sequential grid (the R4 win: 76 -> 67 us), widen
// each thread to 32 B (f32x8 = 2x global_load_dwordx4). Halves wave count,
// doubles per-wave MLP, keeps the moving contiguous window. Both halves of a
// thread's 32 B are always in the same (b,s) row (2i even => 2i and 2i+1 share
// floor(./128)), so one positions load serves both.
// n8 = 5,980,160 = 256 * 23,360 exactly (no tail).

typedef float f32x8 __attribute__((ext_vector_type(8)));

__global__ __launch_bounds__(256, 8)
void PositionalEncoding_80659485819003_kernel(
    const f32x8* __restrict__ x,
    const int*   __restrict__ positions,
    const f32x8* __restrict__ pe,
    f32x8*       __restrict__ out,
    int n8)
{
    const int i = blockIdx.x * 256 + threadIdx.x;
    if (i >= n8) return;

    f32x8 v = __builtin_nontemporal_load(&x[i]);   // 32 B streaming read
    const int row = i >> 6;                        // D/8 = 64 f32x8 per (b,s) row
    const int pos = positions[row];
    if (pos >= 0) {
        v += pe[(pos << 6) + (i & 63)];            // cached gather, 32 B
    }
    __builtin_nontemporal_store(v, &out[i]);       // 32 B streaming write
}

extern "C" void kernel_launch(void* const* d_in, const int* in_sizes, int n_in,
                              void* d_out, int out_size, void* d_ws, size_t ws_size,
                              hipStream_t stream)
{
    const f32x8* x         = (const f32x8*)d_in[0];
    const int*   positions = (const int*)d_in[1];
    const f32x8* pe        = (const f32x8*)d_in[2];
    f32x8*       out       = (f32x8*)d_out;

    const int n8 = out_size / 8;                   // 5,980,160 f32x8
    const int block = 256;
    const int grid = (n8 + block - 1) / block;     // 23,360 blocks, exact fit

    PositionalEncoding_80659485819003_kernel<<<grid, block, 0, stream>>>(
        x, positions, pe, out, n8);
}

// Round 6
// 66.839 us; speedup vs baseline: 1.5093x; 1.5093x over previous
//
#include <hip/hip_runtime.h>

// PositionalEncoding: out[b,s,d] = x[b,s,d] + (positions[b,s] >= 0 ? pe[positions[b,s], d] : 0)
// B=256, S=365, D=512, fp32. Memory-bound: read x (191 MB) + write out (191 MB);
// positions (373 KB) and pe (747 KB) are cache-resident.
//
// Round 5 -> 6: R5's f32x8 regressed (67 -> 101 us): each of its two dwordx4
// loads has lanes at stride 32 B (per-instruction coalescing broken). Keep
// R4's per-instruction-contiguous float4 pattern, widen via BLOCK-STRIDE
// unroll x2 instead: thread t handles base+t and base+t+256. Every load/store
// instruction stays lane-contiguous (16 B/lane), block covers a contiguous
// 8 KB window, 2 independent chains/thread, half the waves of R4.
// n4 = 11,960,320 = 512 * 23,360 exactly (no tail).

typedef float f32x4 __attribute__((ext_vector_type(4)));

__global__ __launch_bounds__(256, 8)
void PositionalEncoding_80659485819003_kernel(
    const f32x4* __restrict__ x,
    const int*   __restrict__ positions,
    const f32x4* __restrict__ pe,
    f32x4*       __restrict__ out,
    int n4)
{
    const int i0 = blockIdx.x * 512 + threadIdx.x;
    const int i1 = i0 + 256;

    if (i1 < n4) {
        f32x4 v0 = __builtin_nontemporal_load(&x[i0]);
        f32x4 v1 = __builtin_nontemporal_load(&x[i1]);
        const int p0 = positions[i0 >> 7];          // D/4 = 128 float4 per row
        const int p1 = positions[i1 >> 7];
        if (p0 >= 0) v0 += pe[(p0 << 7) + (i0 & 127)];
        if (p1 >= 0) v1 += pe[(p1 << 7) + (i1 & 127)];
        __builtin_nontemporal_store(v0, &out[i0]);
        __builtin_nontemporal_store(v1, &out[i1]);
    } else if (i0 < n4) {
        f32x4 v0 = __builtin_nontemporal_load(&x[i0]);
        const int p0 = positions[i0 >> 7];
        if (p0 >= 0) v0 += pe[(p0 << 7) + (i0 & 127)];
        __builtin_nontemporal_store(v0, &out[i0]);
    }
}

extern "C" void kernel_launch(void* const* d_in, const int* in_sizes, int n_in,
                              void* d_out, int out_size, void* d_ws, size_t ws_size,
                              hipStream_t stream)
{
    const f32x4* x         = (const f32x4*)d_in[0];
    const int*   positions = (const int*)d_in[1];
    const f32x4* pe        = (const f32x4*)d_in[2];
    f32x4*       out       = (f32x4*)d_out;

    const int n4 = out_size / 4;                   // 11,960,320 float4
    const int per_block = 512;                     // 2 float4 per thread, block-stride
    const int grid = (n4 + per_block - 1) / per_block;  // 23,360 blocks, exact fit

    PositionalEncoding_80659485819003_kernel<<<grid, 256, 0, stream>>>(
        x, positions, pe, out, n4);
}